// Round 16
// baseline (257.543 us; speedup 1.0000x reference)
//
#include <hip/hip_runtime.h>
#include <stdint.h>

// DetectionLoss for B=16, N=884736. Output: [cls_pos_loss, cls_neg_loss].
//
// R15: mono 59.5us + select_k ~5 + memset ~1.5 but total 85 => ~18us of
// inter-dispatch gaps. R16: FUSE everything into one kernel. Last mono block
// per sample (ticket) becomes that sample's selector (keys-only in LDS, 12KB
// -> occupancy preserved); global ticket -> 16th selector writes out[0..2].
// Mono body identical to R15; selection semantics identical to R6-R15.

#define BATCH 16
#define NPTS 884736u
#define THRESH_KEY 8266976u    // candidate keys >= this (tail 0.01450)
#define THRESH_W   4232691712u // THRESH_KEY<<9 (raw-word compare)
#define KEYMAX 8388607u
#define KSEL 10000u
// cut0 = 2^23 - KSEL*121632/12822 ~= 8293746 ; margin 8000 ~= 8.5 sigma
#define TLO 8285746u
#define THI 8301746u
#define TLO_W 4242301952u      // TLO<<9
#define HI_W  4250494464u      // (THI+1)<<9 : kw>=HI_W <=> key>THI
#define WCAP 3072u             // global window cap/sample (E~1687, sd 41)
#define LCAP 64                // per-block LDS window staging (E~3.9)
#define SCAP 160               // per-block flagged staging (E~31, Poisson)
#define BCAP 64
#define NBLK 432u              // grid.x ; 432*2048 = NPTS
#define EPT 8u
#define HDRB 512               // per-sample header stride

// hdr line (512B/sample): +0 f32 pos_sum, +4 u32 npos (A)
//   +64 u32 cand_total (B) | +128 u32 n_hi, +132 f32 sum_hi (C)
//   +192 u32 n_win, +196 u32 fail, +200 u32 blk_ticket (D)
//   +256 f32 neg_result (E).  gticket: hdr + BATCH*HDRB - 4.

struct KeyPairs { unsigned k[2 * BATCH]; };

__host__ __device__ __forceinline__ void tf2x32(unsigned k0, unsigned k1,
                                                unsigned x0, unsigned x1,
                                                unsigned& o0, unsigned& o1)
{
  unsigned ks0 = k0, ks1 = k1, ks2 = k0 ^ k1 ^ 0x1BD11BDAu;
  x0 += ks0; x1 += ks1;
#define TF_R(r) { x0 += x1; x1 = __builtin_rotateleft32(x1, r); x1 ^= x0; }
  TF_R(13) TF_R(15) TF_R(26) TF_R(6)
  x0 += ks1; x1 += ks2 + 1u;
  TF_R(17) TF_R(29) TF_R(16) TF_R(24)
  x0 += ks2; x1 += ks0 + 2u;
  TF_R(13) TF_R(15) TF_R(26) TF_R(6)
  x0 += ks0; x1 += ks1 + 3u;
  TF_R(17) TF_R(29) TF_R(16) TF_R(24)
  x0 += ks1; x1 += ks2 + 4u;
  TF_R(13) TF_R(15) TF_R(26) TF_R(6)
  x0 += ks2; x1 += ks0 + 5u;
#undef TF_R
  o0 = x0; o1 = x1;
}

__device__ __forceinline__ float lossf(float x, float t, float m)
{
  float e  = __expf(-x);
  float p  = __fdividef(1.0f, 1.0f + e);
  p = fminf(fmaxf(p, 1e-4f), 1.0f - 1e-4f);
  bool is_pos = (t == 1.0f);
  float alpha = is_pos ? 0.75f : 0.25f;
  float pw = is_pos ? (1.0f - p) : p;
  float soft = __logf(1.0f + __expf(-fabsf(x)));
  float bce = fmaxf(x, 0.0f) - x * t + soft;
  float L = (m == 0.0f) ? alpha * pw * pw * bce : 0.0f;
  if (is_pos && p < 0.8f) L *= 4.0f;
  if (!is_pos && p > 0.5f)
    L *= 1.5f + fminf(fmaxf((p - 0.5f) * 5.0f, 0.0f), 1.0f) * 0.5f;
  return L;
}

__global__ __launch_bounds__(256) void fused(
    const float* __restrict__ pred, const float* __restrict__ target,
    const float* __restrict__ mask, char* __restrict__ hdr,
    unsigned* __restrict__ wkey, unsigned* __restrict__ widx,
    float* __restrict__ wloss, float* __restrict__ out, KeyPairs kp)
{
  const int b = blockIdx.y;
  const int tid = threadIdx.x;
  const unsigned i0 = (blockIdx.x * 256u + tid) * EPT;
  const size_t sbase = (size_t)b * NPTS;
  const size_t off = sbase + i0;
  const unsigned k0 = kp.k[2 * b], k1 = kp.k[2 * b + 1];
  char* line = hdr + (size_t)b * HDRB;
  unsigned* gticket = (unsigned*)(hdr + (size_t)BATCH * HDRB - 4);

  // ---- LDS (mono staging + selector arrays; sum ~17.5KB, 8 blocks/CU) ----
  __shared__ unsigned s_n, s_wn, s_base, s_candhi, s_pos, s_tick;
  __shared__ float    s_psum, s_hsum;
  __shared__ unsigned s_si[SCAP], s_skey[SCAP];
  __shared__ unsigned s_wk[LCAP], s_wi[LCAP];
  __shared__ float    s_wl[LCAP];
  __shared__ unsigned skey[WCAP];          // selector: window keys (12KB)
  __shared__ unsigned redu[256];
  __shared__ float    redf[256];
  __shared__ unsigned s_eqc, s_u1, s_fin;
  __shared__ unsigned s_eqi[BCAP];
  __shared__ float    s_eql[BCAP];
  __shared__ float    s_f;
  __shared__ unsigned h_cnt, h_nhi, h_nwin, h_fail, h_npos;
  __shared__ float    h_sumhi;

  if (tid == 0) {
    s_n = 0; s_wn = 0; s_candhi = 0; s_pos = 0;
    s_psum = 0.0f; s_hsum = 0.0f;
  }
  __syncthreads();

  // ===================== mono phase (identical to R15) =====================
  float4 t4a = *reinterpret_cast<const float4*>(target + off);
  float4 t4b = *reinterpret_cast<const float4*>(target + off + 4);
  float tv[8] = { t4a.x, t4a.y, t4a.z, t4a.w, t4b.x, t4b.y, t4b.z, t4b.w };

  unsigned kw[8];
#pragma unroll
  for (int r = 0; r < 8; ++r) {
    unsigned o0, o1;
    tf2x32(k0, k1, 0u, i0 + (unsigned)r, o0, o1);   // partitionable: (0, i)
    kw[r] = o0 ^ o1;                                 // raw word; key = kw>>9
  }

  unsigned candm = 0, posm = 0, him = 0, winm = 0;
#pragma unroll
  for (int r = 0; r < 8; ++r) {
    bool c  = (tv[r] == 0.0f) && (kw[r] >= THRESH_W);
    bool hi = c && (kw[r] >= HI_W);
    bool wn = c && !hi && (kw[r] >= TLO_W);
    candm |= (unsigned)c  << r;
    him   |= (unsigned)hi << r;
    winm  |= (unsigned)wn << r;
    posm  |= (unsigned)(tv[r] == 1.0f) << r;
  }

  if (candm) atomicAdd(&s_candhi, (unsigned)__popc(candm) | ((unsigned)__popc(him) << 16));
  if (posm)  atomicAdd(&s_pos, (unsigned)__popc(posm));

  const unsigned flags = him | winm | posm;
  if (flags) {
#pragma unroll
    for (int r = 0; r < 8; ++r) {
      if ((flags >> r) & 1u) {
        unsigned cls = ((posm >> r) & 1u) ? 2u : (((winm >> r) & 1u) ? 1u : 0u);
        unsigned p = atomicAdd(&s_n, 1u);
        if (p < SCAP) {
          s_si[p] = (i0 + (unsigned)r) | (cls << 20);
          s_skey[p] = kw[r] >> 9;
        } else {
          float x = pred[off + r], m = mask[off + r];
          float L = lossf(x, (cls == 2u) ? 1.0f : 0.0f, m);
          if (cls == 2u) atomicAdd(&s_psum, L);
          else if (cls == 0u) atomicAdd(&s_hsum, L);
          else {
            unsigned w = atomicAdd(&s_wn, 1u);
            if (w < LCAP) { s_wk[w] = kw[r] >> 9; s_wi[w] = i0 + (unsigned)r; s_wl[w] = L; }
          }
        }
      }
    }
  }
  __syncthreads();

  unsigned n = s_n < SCAP ? s_n : SCAP;
  for (unsigned e = tid; e < n; e += 256) {
    unsigned rec = s_si[e];
    unsigned i = rec & 0xFFFFFu, cls = rec >> 20;
    float x = pred[sbase + i], m = mask[sbase + i];
    float L = lossf(x, (cls == 2u) ? 1.0f : 0.0f, m);
    if (cls == 2u) atomicAdd(&s_psum, L);
    else if (cls == 0u) atomicAdd(&s_hsum, L);
    else {
      unsigned w = atomicAdd(&s_wn, 1u);
      if (w < LCAP) { s_wk[w] = s_skey[e]; s_wi[w] = i; s_wl[w] = L; }
    }
  }
  __syncthreads();

  if (tid == 0) {
    unsigned c = s_candhi & 0xFFFFu, h = s_candhi >> 16, p = s_pos;
    if (c) atomicAdd((unsigned*)(line + 64), c);
    if (h) { atomicAdd((unsigned*)(line + 128), h); atomicAdd((float*)(line + 132), s_hsum); }
    if (p) { atomicAdd((unsigned*)(line + 4), p); atomicAdd((float*)(line + 0), s_psum); }
    unsigned wn = s_wn;
    if (wn > LCAP) { atomicOr((unsigned*)(line + 196), 1u); wn = LCAP; }
    s_base = wn ? atomicAdd((unsigned*)(line + 192), wn) : 0u;
    s_wn = wn;
  }
  __syncthreads();
  {
    unsigned wn = s_wn, gb = s_base;
    for (unsigned e = tid; e < wn; e += 256) {
      unsigned g = gb + e;
      if (g < WCAP) {
        wkey[b * WCAP + g] = s_wk[e];
        widx[b * WCAP + g] = s_wi[e];
        wloss[b * WCAP + g] = s_wl[e];
      }
    }
  }

  // ===================== sample ticket: last block selects ================
  if (tid == 0) {
    __threadfence();
    s_tick = atomicAdd((unsigned*)(line + 200), 1u);
  }
  __syncthreads();
  if (s_tick != NBLK - 1) return;

  // ===================== selector phase ===================================
  if (tid == 0) {
    h_cnt   = atomicAdd((unsigned*)(line + 64), 0u);
    h_nhi   = atomicAdd((unsigned*)(line + 128), 0u);
    h_sumhi = atomicAdd((float*)(line + 132), 0.0f);
    h_nwin  = atomicAdd((unsigned*)(line + 192), 0u);
    h_fail  = atomicAdd((unsigned*)(line + 196), 0u);
    h_npos  = atomicAdd((unsigned*)(line + 4), 0u);
  }
  __syncthreads();
  const unsigned cnt = h_cnt, n_hi = h_nhi, n_win = h_nwin, fail = h_fail,
                 npos = h_npos;
  const float sum_hi = h_sumhi;
  const bool take_all = (cnt <= KSEL);
  const unsigned nsel = take_all ? cnt : KSEL;
  const unsigned k = (npos > 0u) ? ((100u * npos < KSEL) ? 100u * npos : KSEL) : 100u;
  const bool bad = fail || take_all || (n_hi > KSEL) ||
                   (n_hi + n_win < KSEL) || (n_win > WCAP) || (k < nsel);

  auto redSumU = [&](unsigned v) -> unsigned {
    redu[tid] = v; __syncthreads();
    for (int s = 128; s > 0; s >>= 1) { if (tid < s) redu[tid] += redu[tid + s]; __syncthreads(); }
    unsigned r = redu[0]; __syncthreads(); return r;
  };
  auto redSumF = [&](float v) -> float {
    redf[tid] = v; __syncthreads();
    for (int s = 128; s > 0; s >>= 1) { if (tid < s) redf[tid] += redf[tid + s]; __syncthreads(); }
    float r = redf[0]; __syncthreads(); return r;
  };

  float res = 0.0f;

  if (!bad) {
    const unsigned nw = n_win;
    for (unsigned e = tid; e < nw; e += 256) skey[e] = wkey[b * WCAP + e];
    __syncthreads();
    const unsigned need = KSEL - n_hi;
    if (need == 0) res = sum_hi;
    else {
      auto cGe = [&](unsigned v) -> unsigned {
        unsigned c = 0;
        for (unsigned e = tid; e < nw; e += 256) c += (skey[e] >= v) ? 1u : 0u;
        return redSumU(c);
      };
      unsigned lo = TLO, hi = THI;                 // cGe(TLO)=nw>=need
      while (lo < hi) {
        unsigned mid = lo + (hi - lo + 1u) / 2u;
        if (cGe(mid) >= need) lo = mid; else hi = mid - 1u;
      }
      const unsigned V = lo;
      const unsigned c_gt = cGe(V + 1u);
      const unsigned m = need - c_gt;
      float s = 0.0f;
      for (unsigned e = tid; e < nw; e += 256)
        if (skey[e] > V) s += wloss[b * WCAP + e];
      float sum_gt = redSumF(s);
      if (tid == 0) s_eqc = 0;
      __syncthreads();
      for (unsigned e = tid; e < nw; e += 256) {
        if (skey[e] == V) {
          unsigned p = atomicAdd(&s_eqc, 1u);
          if (p < BCAP) { s_eqi[p] = widx[b * WCAP + e]; s_eql[p] = wloss[b * WCAP + e]; }
        }
      }
      __syncthreads();
      if (tid == 0) {
        unsigned ne = s_eqc; if (ne > BCAP) ne = BCAP;
        unsigned mm = (m < ne) ? m : ne;
        float es = 0.0f;
        for (unsigned a = 0; a < mm; ++a) {        // idx asc (LDS only)
          unsigned best = a;
          for (unsigned q = a + 1; q < ne; ++q)
            if (s_eqi[q] < s_eqi[best]) best = q;
          unsigned ti = s_eqi[a]; s_eqi[a] = s_eqi[best]; s_eqi[best] = ti;
          float tl = s_eql[a]; s_eql[a] = s_eql[best]; s_eql[best] = tl;
          es += s_eql[a];
        }
        s_f = sum_hi + sum_gt + es;
      }
      __syncthreads();
      res = s_f;
    }
  } else {
    // ---- exact fallback via full rescans (dead for this data) ----
    const float* T = target + sbase;
    const float* P = pred   + sbase;
    const float* M = mask   + sbase;
    auto keyOf = [&](unsigned i) -> unsigned {
      unsigned o0, o1; tf2x32(k0, k1, 0u, i, o0, o1); return (o0 ^ o1) >> 9;
    };
    auto cKeyGe = [&](unsigned v) -> unsigned {
      unsigned c = 0;
      for (unsigned i = tid; i < NPTS; i += 256)
        if (T[i] == 0.0f && keyOf(i) >= v) c++;
      return redSumU(c);
    };
    unsigned V = 0, idxcut = 0xffffffffu; float eq_sum = 0.0f;
    if (!take_all) {
      unsigned lo = THRESH_KEY, hi = KEYMAX;
      while (lo < hi) {
        unsigned mid = lo + (hi - lo + 1u) / 2u;
        if (cKeyGe(mid) >= KSEL) lo = mid; else hi = mid - 1u;
      }
      V = lo;
      unsigned c_gt = cKeyGe(V + 1u);
      unsigned needq = KSEL - c_gt;
      if (tid == 0) s_eqc = 0;
      __syncthreads();
      for (unsigned i = tid; i < NPTS; i += 256)
        if (T[i] == 0.0f && keyOf(i) == V) {
          unsigned p = atomicAdd(&s_eqc, 1u);
          if (p < BCAP) s_eqi[p] = i;
        }
      __syncthreads();
      if (tid == 0) {
        unsigned ne = s_eqc; if (ne > BCAP) ne = BCAP;
        unsigned mm = (needq < ne) ? needq : ne;
        float es = 0.0f; unsigned ic = 0xffffffffu;
        for (unsigned a = 0; a < mm; ++a) {
          unsigned best = a;
          for (unsigned q = a + 1; q < ne; ++q)
            if (s_eqi[q] < s_eqi[best]) best = q;
          unsigned ti = s_eqi[a]; s_eqi[a] = s_eqi[best]; s_eqi[best] = ti;
          es += lossf(P[s_eqi[a]], 0.0f, M[s_eqi[a]]);
        }
        if (mm > 0) ic = s_eqi[mm - 1];
        s_f = es; s_u1 = ic;
      }
      __syncthreads();
      eq_sum = s_f; idxcut = s_u1;
      __syncthreads();
    }
    if (k >= nsel) {
      float s = 0.0f;
      for (unsigned i = tid; i < NPTS; i += 256) {
        if (T[i] != 0.0f) continue;
        unsigned kk = keyOf(i);
        if (kk < THRESH_KEY) continue;
        if (take_all || kk > V) s += lossf(P[i], 0.0f, M[i]);
      }
      res = redSumF(s) + (take_all ? 0.0f : eq_sum);
    } else {
      auto cLossGe = [&](unsigned w) -> unsigned {
        unsigned c = 0;
        for (unsigned i = tid; i < NPTS; i += 256) {
          if (T[i] != 0.0f) continue;
          unsigned kk = keyOf(i);
          if (kk < THRESH_KEY) continue;
          bool sel = take_all || kk > V || (kk == V && i <= idxcut);
          if (sel && __float_as_uint(lossf(P[i], 0.0f, M[i])) >= w) c++;
        }
        return redSumU(c);
      };
      unsigned lo = 0u, hi = 0x7f7fffffu;
      while (lo < hi) {
        unsigned mid = lo + (hi - lo + 1u) / 2u;
        if (cLossGe(mid) >= k) lo = mid; else hi = mid - 1u;
      }
      unsigned cgt = cLossGe(lo + 1u);
      float s = 0.0f;
      for (unsigned i = tid; i < NPTS; i += 256) {
        if (T[i] != 0.0f) continue;
        unsigned kk = keyOf(i);
        if (kk < THRESH_KEY) continue;
        bool sel = take_all || kk > V || (kk == V && i <= idxcut);
        float L = lossf(P[i], 0.0f, M[i]);
        if (sel && __float_as_uint(L) > lo) s += L;
      }
      res = redSumF(s) + (float)(k - cgt) * __uint_as_float(lo);
    }
  }

  // ============ publish + global ticket: 16th selector finalizes ==========
  if (tid == 0) {
    atomicExch((float*)(line + 256), res);
    __threadfence();
    s_fin = atomicAdd(gticket, 1u);
  }
  __syncthreads();
  if (s_fin == BATCH - 1) {
    float ps = 0.0f, ns = 0.0f;
    if (tid < BATCH) {
      char* ln = hdr + (size_t)tid * HDRB;
      float pp = atomicAdd((float*)(ln + 0), 0.0f);
      unsigned np = atomicAdd((unsigned*)(ln + 4), 0u);
      float nr = atomicAdd((float*)(ln + 256), 0.0f);
      float denom = (np > 0u) ? fmaxf((float)np, 1.0f) : 1.0f;
      ps = pp / denom;
      ns = nr / denom;
    }
#pragma unroll
    for (int s = 8; s > 0; s >>= 1) {
      ps += __shfl_down(ps, s, 64);
      ns += __shfl_down(ns, s, 64);
    }
    if (tid == 0) {
      out[0] = ps / (float)BATCH;
      out[1] = ns / (float)BATCH;
    }
  }
}

extern "C" void kernel_launch(void* const* d_in, const int* in_sizes, int n_in,
                              void* d_out, int out_size, void* d_ws, size_t ws_size,
                              hipStream_t stream)
{
  const float* pred   = (const float*)d_in[0];
  const float* target = (const float*)d_in[1];
  const float* mask   = (const float*)d_in[2];
  float* out = (float*)d_out;

  const size_t HDRSZ = (size_t)BATCH * HDRB;                       // 8192
  const size_t FIXED = HDRSZ + 3 * (size_t)BATCH * WCAP * 4;       // 598016
  if (ws_size < FIXED || out_size < 2) {
    hipMemsetAsync(d_out, 0, sizeof(float) * (out_size > 0 ? out_size : 1), stream);
    return;
  }

  char* ws = (char*)d_ws;
  char*     hdr   = ws;
  unsigned* wkey  = (unsigned*)(ws + HDRSZ);
  unsigned* widx  = wkey + (size_t)BATCH * WCAP;
  float*    wloss = (float*)(widx + (size_t)BATCH * WCAP);

  KeyPairs kp;
  for (unsigned b = 0; b < BATCH; ++b) {
    unsigned o0, o1;
    tf2x32(0u, 42u, 0u, b, o0, o1);
    kp.k[2 * b] = o0; kp.k[2 * b + 1] = o1;
  }

  hipMemsetAsync(hdr, 0, HDRSZ, stream);   // zeroes counters + tickets

  fused<<<dim3(NBLK, BATCH), 256, 0, stream>>>(pred, target, mask, hdr,
                                               wkey, widx, wloss, out, kp);
}

// Round 19
// 75.787 us; speedup vs baseline: 3.3982x; 3.3982x over previous
//
#include <hip/hip_runtime.h>
#include <stdint.h>

// DetectionLoss for B=16, N=884736. Output: [cls_pos_loss, cls_neg_loss].
//
// R16 lesson: single-kernel fusion needs per-block device-scope fences
// (cross-XCD L2 non-coherence) -> L2 writeback per block -> 3x regression.
// R17-R19: back to R15's 2-kernel structure (proven 85us) with mono slimmed:
//  - no cand_total (bad-check via n_hi+n_win; fallback rescans exact cnt)
//  - one reservation atomic per flagged thread (popc), not per slot
//  - n_hi/npos counted in the compacted phase (rare-path atomics)
//  - compacted phase = single tid<n step; window appended to GLOBAL via
//    wave-ballot aggregated reservation (no LDS window arrays, 3 barriers)
// Selection semantics identical to R6-R15 (absmax 0.0 expected).
// (R19 = R17 resubmitted; rounds 17/18 died to infra before running.)

#define BATCH 16
#define NPTS 884736u
#define THRESH_KEY 8266976u    // candidate keys >= this (tail 0.01450)
#define THRESH_W   4232691712u // THRESH_KEY<<9 (raw-word compare)
#define KEYMAX 8388607u
#define KSEL 10000u
// cut0 = 2^23 - KSEL*121632/12822 ~= 8293746 ; margin 8000 ~= 8.5 sigma
#define TLO 8285746u
#define THI 8301746u
#define TLO_W 4242301952u      // TLO<<9
#define HI_W  4250494464u      // (THI+1)<<9 : kw>=HI_W <=> key>THI
#define WCAP 3072u             // global window cap/sample (E~1687, sd 41)
#define SCAP 160               // per-block flagged staging (E~31, Poisson)
#define BCAP 64
#define NBLK 432u              // mono grid.x ; 432*2048 = NPTS
#define EPT 8u
#define HDRB 512               // per-sample header stride

// hdr line (512B/sample): +0 f32 pos_sum, +4 u32 npos (line A)
//   +128 u32 n_hi, +132 f32 sum_hi (C) | +192 u32 n_win, +196 u32 fail (D)
//   +256 f32 neg_result (E).  gticket: hdr + BATCH*HDRB - 4.

struct KeyPairs { unsigned k[2 * BATCH]; };

__host__ __device__ __forceinline__ void tf2x32(unsigned k0, unsigned k1,
                                                unsigned x0, unsigned x1,
                                                unsigned& o0, unsigned& o1)
{
  unsigned ks0 = k0, ks1 = k1, ks2 = k0 ^ k1 ^ 0x1BD11BDAu;
  x0 += ks0; x1 += ks1;
#define TF_R(r) { x0 += x1; x1 = __builtin_rotateleft32(x1, r); x1 ^= x0; }
  TF_R(13) TF_R(15) TF_R(26) TF_R(6)
  x0 += ks1; x1 += ks2 + 1u;
  TF_R(17) TF_R(29) TF_R(16) TF_R(24)
  x0 += ks2; x1 += ks0 + 2u;
  TF_R(13) TF_R(15) TF_R(26) TF_R(6)
  x0 += ks0; x1 += ks1 + 3u;
  TF_R(17) TF_R(29) TF_R(16) TF_R(24)
  x0 += ks1; x1 += ks2 + 4u;
  TF_R(13) TF_R(15) TF_R(26) TF_R(6)
  x0 += ks2; x1 += ks0 + 5u;
#undef TF_R
  o0 = x0; o1 = x1;
}

__device__ __forceinline__ float lossf(float x, float t, float m)
{
  float e  = __expf(-x);
  float p  = __fdividef(1.0f, 1.0f + e);
  p = fminf(fmaxf(p, 1e-4f), 1.0f - 1e-4f);
  bool is_pos = (t == 1.0f);
  float alpha = is_pos ? 0.75f : 0.25f;
  float pw = is_pos ? (1.0f - p) : p;
  float soft = __logf(1.0f + __expf(-fabsf(x)));
  float bce = fmaxf(x, 0.0f) - x * t + soft;
  float L = (m == 0.0f) ? alpha * pw * pw * bce : 0.0f;
  if (is_pos && p < 0.8f) L *= 4.0f;
  if (!is_pos && p > 0.5f)
    L *= 1.5f + fminf(fmaxf((p - 0.5f) * 5.0f, 0.0f), 1.0f) * 0.5f;
  return L;
}

__global__ __launch_bounds__(256) void mono(
    const float* __restrict__ pred, const float* __restrict__ target,
    const float* __restrict__ mask, char* __restrict__ hdr,
    unsigned* __restrict__ wkey, unsigned* __restrict__ widx,
    float* __restrict__ wloss, KeyPairs kp)
{
  const int b = blockIdx.y;
  const int tid = threadIdx.x;
  const unsigned i0 = (blockIdx.x * 256u + tid) * EPT;
  const size_t sbase = (size_t)b * NPTS;
  const size_t off = sbase + i0;
  const unsigned k0 = kp.k[2 * b], k1 = kp.k[2 * b + 1];
  char* line = hdr + (size_t)b * HDRB;

  __shared__ unsigned s_n, s_nhi, s_npos;
  __shared__ float    s_psum, s_hsum;
  __shared__ unsigned s_si[SCAP], s_skey[SCAP];

  if (tid == 0) { s_n = 0; s_nhi = 0; s_npos = 0; s_psum = 0.0f; s_hsum = 0.0f; }
  __syncthreads();

  float4 t4a = *reinterpret_cast<const float4*>(target + off);
  float4 t4b = *reinterpret_cast<const float4*>(target + off + 4);
  float tv[8] = { t4a.x, t4a.y, t4a.z, t4a.w, t4b.x, t4b.y, t4b.z, t4b.w };

  unsigned kw[8];
#pragma unroll
  for (int r = 0; r < 8; ++r) {
    unsigned o0, o1;
    tf2x32(k0, k1, 0u, i0 + (unsigned)r, o0, o1);   // partitionable: (0, i)
    kw[r] = o0 ^ o1;                                 // raw word; key = kw>>9
  }

  unsigned posm = 0, him = 0, winm = 0;
#pragma unroll
  for (int r = 0; r < 8; ++r) {
    bool c  = (tv[r] == 0.0f) && (kw[r] >= THRESH_W);
    bool hi = c && (kw[r] >= HI_W);
    bool wn = c && !hi && (kw[r] >= TLO_W);
    him   |= (unsigned)hi << r;
    winm  |= (unsigned)wn << r;
    posm  |= (unsigned)(tv[r] == 1.0f) << r;
  }

  // stage flagged elements (idx|class): class 0=hi 1=win 2=pos
  const unsigned flags = him | winm | posm;
  if (flags) {
    unsigned nf = (unsigned)__popc(flags);
    unsigned base = atomicAdd(&s_n, nf);
    unsigned j = 0;
#pragma unroll
    for (int r = 0; r < 8; ++r) {
      if ((flags >> r) & 1u) {
        unsigned cls = ((posm >> r) & 1u) ? 2u : (((winm >> r) & 1u) ? 1u : 0u);
        unsigned p = base + j; ++j;
        if (p < SCAP) {
          s_si[p] = (i0 + (unsigned)r) | (cls << 20);
          s_skey[p] = kw[r] >> 9;
        } else {
          // inline overflow path (probability ~0): exact regardless
          float x = pred[off + r], m = mask[off + r];
          float L = lossf(x, (cls == 2u) ? 1.0f : 0.0f, m);
          if (cls == 2u) { atomicAdd(&s_psum, L); atomicAdd(&s_npos, 1u); }
          else if (cls == 0u) { atomicAdd(&s_hsum, L); atomicAdd(&s_nhi, 1u); }
          else {
            unsigned g = atomicAdd((unsigned*)(line + 192), 1u);
            if (g < WCAP) {
              wkey[b * WCAP + g] = kw[r] >> 9;
              widx[b * WCAP + g] = i0 + (unsigned)r;
              wloss[b * WCAP + g] = L;
            } else atomicOr((unsigned*)(line + 196), 1u);
          }
        }
      }
    }
  }
  __syncthreads();

  // compacted processing: n <= SCAP < 256 -> single step
  const unsigned n = s_n < SCAP ? s_n : SCAP;
  unsigned rec = (tid < (int)n) ? s_si[tid] : 0u;
  unsigned cls = (tid < (int)n) ? (rec >> 20) : 3u;
  unsigned i = rec & 0xFFFFFu;
  float L = 0.0f;
  if (cls < 3u) {
    float x = pred[sbase + i], m = mask[sbase + i];
    L = lossf(x, (cls == 2u) ? 1.0f : 0.0f, m);
  }
  if (cls == 2u) { atomicAdd(&s_psum, L); atomicAdd(&s_npos, 1u); }
  else if (cls == 0u) { atomicAdd(&s_hsum, L); atomicAdd(&s_nhi, 1u); }
  // window: wave-aggregated global append
  {
    bool isw = (cls == 1u);
    unsigned long long mv = __ballot(isw ? 1 : 0);
    if (isw) {
      int lane = tid & 63;
      unsigned rank = (unsigned)__popcll(mv & ((1ull << lane) - 1ull));
      int leader = __ffsll((unsigned long long)mv) - 1;
      unsigned gb = 0;
      if (lane == leader)
        gb = atomicAdd((unsigned*)(line + 192), (unsigned)__popcll(mv));
      gb = __shfl(gb, leader, 64);
      unsigned g = gb + rank;
      if (g < WCAP) {
        wkey[b * WCAP + g] = s_skey[tid];
        widx[b * WCAP + g] = i;
        wloss[b * WCAP + g] = L;
      } else atomicOr((unsigned*)(line + 196), 1u);
    }
  }
  __syncthreads();

  if (tid == 0) {
    if (s_nhi) { atomicAdd((unsigned*)(line + 128), s_nhi); atomicAdd((float*)(line + 132), s_hsum); }
    if (s_npos) { atomicAdd((unsigned*)(line + 4), s_npos); atomicAdd((float*)(line + 0), s_psum); }
  }
}

// select_k: 16 blocks. Window selection in LDS (normal), full-rescan exact
// fallback (dead). Last block (gticket) computes the final 2-float output.
__global__ __launch_bounds__(256) void select_k(
    const float* __restrict__ pred, const float* __restrict__ target,
    const float* __restrict__ mask, char* __restrict__ hdr,
    const unsigned* __restrict__ wkey, const unsigned* __restrict__ widx,
    const float* __restrict__ wloss, float* __restrict__ out, KeyPairs kp)
{
  const int b = blockIdx.x;
  const int tid = threadIdx.x;
  char* line = hdr + (size_t)b * HDRB;
  unsigned* gticket = (unsigned*)(hdr + (size_t)BATCH * HDRB - 4);

  __shared__ unsigned skey[WCAP], sidx[WCAP];
  __shared__ float    sls[WCAP];
  __shared__ unsigned redu[256];
  __shared__ float    redf[256];
  __shared__ unsigned s_eqc, s_u1, s_tick;
  __shared__ unsigned s_eqi[BCAP];
  __shared__ float    s_eql[BCAP];
  __shared__ float    s_f;

  const unsigned n_hi   = *(const unsigned*)(line + 128);
  const float    sum_hi = *(const float*)(line + 132);
  const unsigned n_win  = *(const unsigned*)(line + 192);
  const unsigned fail   = *(const unsigned*)(line + 196);
  const unsigned npos   = *(const unsigned*)(line + 4);
  const unsigned k = (npos > 0u) ? ((100u * npos < KSEL) ? 100u * npos : KSEL) : 100u;
  const bool bad = fail || (n_hi > KSEL) || (n_hi + n_win < KSEL) ||
                   (n_win > WCAP) || (k < KSEL);

  auto redSumU = [&](unsigned v) -> unsigned {
    redu[tid] = v; __syncthreads();
    for (int s = 128; s > 0; s >>= 1) { if (tid < s) redu[tid] += redu[tid + s]; __syncthreads(); }
    unsigned r = redu[0]; __syncthreads(); return r;
  };
  auto redSumF = [&](float v) -> float {
    redf[tid] = v; __syncthreads();
    for (int s = 128; s > 0; s >>= 1) { if (tid < s) redf[tid] += redf[tid + s]; __syncthreads(); }
    float r = redf[0]; __syncthreads(); return r;
  };

  float res = 0.0f;

  if (!bad) {
    // cnt > KSEL guaranteed (n_hi + n_win > KSEL, all are candidates)
    const unsigned nw = n_win;
    for (unsigned e = tid; e < nw; e += 256) {
      skey[e] = wkey[b * WCAP + e];
      sidx[e] = widx[b * WCAP + e];
      sls[e]  = wloss[b * WCAP + e];
    }
    __syncthreads();
    const unsigned need = KSEL - n_hi;
    if (need == 0) res = sum_hi;
    else {
      auto cGe = [&](unsigned v) -> unsigned {
        unsigned c = 0;
        for (unsigned e = tid; e < nw; e += 256) c += (skey[e] >= v) ? 1u : 0u;
        return redSumU(c);
      };
      unsigned lo = TLO, hi = THI;                 // cGe(TLO)=nw>=need
      while (lo < hi) {
        unsigned mid = lo + (hi - lo + 1u) / 2u;
        if (cGe(mid) >= need) lo = mid; else hi = mid - 1u;
      }
      const unsigned V = lo;
      const unsigned c_gt = cGe(V + 1u);
      const unsigned m = need - c_gt;
      float s = 0.0f;
      for (unsigned e = tid; e < nw; e += 256) if (skey[e] > V) s += sls[e];
      float sum_gt = redSumF(s);
      if (tid == 0) s_eqc = 0;
      __syncthreads();
      for (unsigned e = tid; e < nw; e += 256) {
        if (skey[e] == V) {
          unsigned p = atomicAdd(&s_eqc, 1u);
          if (p < BCAP) { s_eqi[p] = sidx[e]; s_eql[p] = sls[e]; }
        }
      }
      __syncthreads();
      if (tid == 0) {
        unsigned ne = s_eqc; if (ne > BCAP) ne = BCAP;
        unsigned mm = (m < ne) ? m : ne;
        float es = 0.0f;
        for (unsigned a = 0; a < mm; ++a) {        // idx asc (LDS only)
          unsigned best = a;
          for (unsigned q = a + 1; q < ne; ++q)
            if (s_eqi[q] < s_eqi[best]) best = q;
          unsigned ti = s_eqi[a]; s_eqi[a] = s_eqi[best]; s_eqi[best] = ti;
          float tl = s_eql[a]; s_eql[a] = s_eql[best]; s_eql[best] = tl;
          es += s_eql[a];
        }
        s_f = sum_hi + sum_gt + es;
      }
      __syncthreads();
      res = s_f;
    }
  } else {
    // ---- exact fallback via full rescans (dead for this data) ----
    const float* T = target + (size_t)b * NPTS;
    const float* P = pred   + (size_t)b * NPTS;
    const float* M = mask   + (size_t)b * NPTS;
    const unsigned k0 = kp.k[2 * b], k1 = kp.k[2 * b + 1];
    auto keyOf = [&](unsigned i) -> unsigned {
      unsigned o0, o1; tf2x32(k0, k1, 0u, i, o0, o1); return (o0 ^ o1) >> 9;
    };
    auto cKeyGe = [&](unsigned v) -> unsigned {
      unsigned c = 0;
      for (unsigned i = tid; i < NPTS; i += 256)
        if (T[i] == 0.0f && keyOf(i) >= v) c++;
      return redSumU(c);
    };
    const unsigned cnt = cKeyGe(THRESH_KEY);       // exact candidate count
    const bool take_all = (cnt <= KSEL);
    const unsigned nsel = take_all ? cnt : KSEL;
    unsigned V = 0, idxcut = 0xffffffffu; float eq_sum = 0.0f;
    if (!take_all) {
      unsigned lo = THRESH_KEY, hi = KEYMAX;
      while (lo < hi) {
        unsigned mid = lo + (hi - lo + 1u) / 2u;
        if (cKeyGe(mid) >= KSEL) lo = mid; else hi = mid - 1u;
      }
      V = lo;
      unsigned c_gt = cKeyGe(V + 1u);
      unsigned needq = KSEL - c_gt;
      if (tid == 0) s_eqc = 0;
      __syncthreads();
      for (unsigned i = tid; i < NPTS; i += 256)
        if (T[i] == 0.0f && keyOf(i) == V) {
          unsigned p = atomicAdd(&s_eqc, 1u);
          if (p < BCAP) s_eqi[p] = i;
        }
      __syncthreads();
      if (tid == 0) {
        unsigned ne = s_eqc; if (ne > BCAP) ne = BCAP;
        unsigned mm = (needq < ne) ? needq : ne;
        float es = 0.0f; unsigned ic = 0xffffffffu;
        for (unsigned a = 0; a < mm; ++a) {
          unsigned best = a;
          for (unsigned q = a + 1; q < ne; ++q)
            if (s_eqi[q] < s_eqi[best]) best = q;
          unsigned ti = s_eqi[a]; s_eqi[a] = s_eqi[best]; s_eqi[best] = ti;
          es += lossf(P[s_eqi[a]], 0.0f, M[s_eqi[a]]);
        }
        if (mm > 0) ic = s_eqi[mm - 1];
        s_f = es; s_u1 = ic;
      }
      __syncthreads();
      eq_sum = s_f; idxcut = s_u1;
      __syncthreads();
    }
    if (k >= nsel) {
      float s = 0.0f;
      for (unsigned i = tid; i < NPTS; i += 256) {
        if (T[i] != 0.0f) continue;
        unsigned kk = keyOf(i);
        if (kk < THRESH_KEY) continue;
        if (take_all || kk > V) s += lossf(P[i], 0.0f, M[i]);
      }
      res = redSumF(s) + (take_all ? 0.0f : eq_sum);
    } else {
      auto cLossGe = [&](unsigned w) -> unsigned {
        unsigned c = 0;
        for (unsigned i = tid; i < NPTS; i += 256) {
          if (T[i] != 0.0f) continue;
          unsigned kk = keyOf(i);
          if (kk < THRESH_KEY) continue;
          bool sel = take_all || kk > V || (kk == V && i <= idxcut);
          if (sel && __float_as_uint(lossf(P[i], 0.0f, M[i])) >= w) c++;
        }
        return redSumU(c);
      };
      unsigned lo = 0u, hi = 0x7f7fffffu;
      while (lo < hi) {
        unsigned mid = lo + (hi - lo + 1u) / 2u;
        if (cLossGe(mid) >= k) lo = mid; else hi = mid - 1u;
      }
      unsigned cgt = cLossGe(lo + 1u);
      float s = 0.0f;
      for (unsigned i = tid; i < NPTS; i += 256) {
        if (T[i] != 0.0f) continue;
        unsigned kk = keyOf(i);
        if (kk < THRESH_KEY) continue;
        bool sel = take_all || kk > V || (kk == V && i <= idxcut);
        float L = lossf(P[i], 0.0f, M[i]);
        if (sel && __float_as_uint(L) > lo) s += L;
      }
      res = redSumF(s) + (float)(k - cgt) * __uint_as_float(lo);
    }
  }

  // publish result (device-scope) and take a ticket; last block finalizes
  if (tid == 0) {
    atomicExch((float*)(line + 256), res);
    __threadfence();
    s_tick = atomicAdd(gticket, 1u);
  }
  __syncthreads();
  if (s_tick == BATCH - 1) {
    float ps = 0.0f, ns = 0.0f;
    if (tid < BATCH) {
      char* ln = hdr + (size_t)tid * HDRB;
      float pp = atomicAdd((float*)(ln + 0), 0.0f);
      unsigned np = atomicAdd((unsigned*)(ln + 4), 0u);
      float nr = atomicAdd((float*)(ln + 256), 0.0f);
      float denom = (np > 0u) ? fmaxf((float)np, 1.0f) : 1.0f;
      ps = pp / denom;
      ns = nr / denom;
    }
#pragma unroll
    for (int s = 8; s > 0; s >>= 1) {
      ps += __shfl_down(ps, s, 64);
      ns += __shfl_down(ns, s, 64);
    }
    if (tid == 0) {
      out[0] = ps / (float)BATCH;
      out[1] = ns / (float)BATCH;
    }
  }
}

extern "C" void kernel_launch(void* const* d_in, const int* in_sizes, int n_in,
                              void* d_out, int out_size, void* d_ws, size_t ws_size,
                              hipStream_t stream)
{
  const float* pred   = (const float*)d_in[0];
  const float* target = (const float*)d_in[1];
  const float* mask   = (const float*)d_in[2];
  float* out = (float*)d_out;

  const size_t HDRSZ = (size_t)BATCH * HDRB;                       // 8192
  const size_t FIXED = HDRSZ + 3 * (size_t)BATCH * WCAP * 4;       // 598016
  if (ws_size < FIXED || out_size < 2) {
    hipMemsetAsync(d_out, 0, sizeof(float) * (out_size > 0 ? out_size : 1), stream);
    return;
  }

  char* ws = (char*)d_ws;
  char*     hdr   = ws;
  unsigned* wkey  = (unsigned*)(ws + HDRSZ);
  unsigned* widx  = wkey + (size_t)BATCH * WCAP;
  float*    wloss = (float*)(widx + (size_t)BATCH * WCAP);

  KeyPairs kp;
  for (unsigned b = 0; b < BATCH; ++b) {
    unsigned o0, o1;
    tf2x32(0u, 42u, 0u, b, o0, o1);
    kp.k[2 * b] = o0; kp.k[2 * b + 1] = o1;
  }

  hipMemsetAsync(hdr, 0, HDRSZ, stream);   // zeroes counters + gticket

  mono<<<dim3(NBLK, BATCH), 256, 0, stream>>>(pred, target, mask, hdr,
                                              wkey, widx, wloss, kp);
  select_k<<<BATCH, 256, 0, stream>>>(pred, target, mask, hdr,
                                      wkey, widx, wloss, out, kp);
}

// Round 20
// 68.289 us; speedup vs baseline: 3.7713x; 1.1098x over previous
//
#include <hip/hip_runtime.h>
#include <stdint.h>

// DetectionLoss for B=16, N=884736. Output: [cls_pos_loss, cls_neg_loss].
//
// R19: 75.8us = mono 52.3 + select ~6 + memset 1.5 + ~16us of 3 dispatch
// gaps. R20: (1) EPT=16 (216 blocks/sample) halves per-block fixed overhead;
// (2) mono writes per-block PARTIALS (own slot, written every launch -> no
// zeroing) + per-block window regions -> zero global atomics in mono and the
// memset dispatch is DELETED (mono zeroes the one ticket word itself);
// (3) select_k reduces partials, scans+gathers window into LDS, then does the
// identical exact selection (tie: lowest idx). 2 dispatches total.

#define BATCH 16
#define NPTS 884736u
#define THRESH_KEY 8266976u    // candidate keys >= this (tail 0.01450)
#define THRESH_W   4232691712u // THRESH_KEY<<9 (raw-word compare)
#define KEYMAX 8388607u
#define KSEL 10000u
// cut0 = 2^23 - KSEL*121632/12822 ~= 8293746 ; margin 8000 ~= 8.5 sigma
#define TLO 8285746u
#define THI 8301746u
#define TLO_W 4242301952u      // TLO<<9
#define HI_W  4250494464u      // (THI+1)<<9 : kw>=HI_W <=> key>THI
#define WCAP 3072u             // selection window LDS cap/sample (E~1687, sd 41)
#define WBCAP 40u              // per-block window region (E~7.8, +11 sigma)
#define SCAP 192               // per-block flagged staging (E~52, +19 sigma)
#define BCAP 64
#define NBLK2 216u             // mono grid.x ; 216*4096 = NPTS
#define EPT 16u
#define HDRB 512               // per-sample header stride (hdr = 8192 B)

// ws layout: [0,8192) hdr  (line b: +0 f32 pos_sum, +4 u32 npos,
//   +256 f32 neg_result; gticket at ws+8188)
// [8192,..)   p_nhi/p_hsum/p_npos/p_psum/p_nwin : 5 x u32[3456]
// [77312,..)  wkey/widx/wloss : 3 x [3456][WBCAP]
#define OFF_PART 8192
#define PARTN (NBLK2 * BATCH)          // 3456
#define OFF_WIN (OFF_PART + 5 * PARTN * 4)

struct KeyPairs { unsigned k[2 * BATCH]; };

__host__ __device__ __forceinline__ void tf2x32(unsigned k0, unsigned k1,
                                                unsigned x0, unsigned x1,
                                                unsigned& o0, unsigned& o1)
{
  unsigned ks0 = k0, ks1 = k1, ks2 = k0 ^ k1 ^ 0x1BD11BDAu;
  x0 += ks0; x1 += ks1;
#define TF_R(r) { x0 += x1; x1 = __builtin_rotateleft32(x1, r); x1 ^= x0; }
  TF_R(13) TF_R(15) TF_R(26) TF_R(6)
  x0 += ks1; x1 += ks2 + 1u;
  TF_R(17) TF_R(29) TF_R(16) TF_R(24)
  x0 += ks2; x1 += ks0 + 2u;
  TF_R(13) TF_R(15) TF_R(26) TF_R(6)
  x0 += ks0; x1 += ks1 + 3u;
  TF_R(17) TF_R(29) TF_R(16) TF_R(24)
  x0 += ks1; x1 += ks2 + 4u;
  TF_R(13) TF_R(15) TF_R(26) TF_R(6)
  x0 += ks2; x1 += ks0 + 5u;
#undef TF_R
  o0 = x0; o1 = x1;
}

__device__ __forceinline__ float lossf(float x, float t, float m)
{
  float e  = __expf(-x);
  float p  = __fdividef(1.0f, 1.0f + e);
  p = fminf(fmaxf(p, 1e-4f), 1.0f - 1e-4f);
  bool is_pos = (t == 1.0f);
  float alpha = is_pos ? 0.75f : 0.25f;
  float pw = is_pos ? (1.0f - p) : p;
  float soft = __logf(1.0f + __expf(-fabsf(x)));
  float bce = fmaxf(x, 0.0f) - x * t + soft;
  float L = (m == 0.0f) ? alpha * pw * pw * bce : 0.0f;
  if (is_pos && p < 0.8f) L *= 4.0f;
  if (!is_pos && p > 0.5f)
    L *= 1.5f + fminf(fmaxf((p - 0.5f) * 5.0f, 0.0f), 1.0f) * 0.5f;
  return L;
}

__global__ __launch_bounds__(256) void mono(
    const float* __restrict__ pred, const float* __restrict__ target,
    const float* __restrict__ mask, char* __restrict__ ws, KeyPairs kp)
{
  const int b = blockIdx.y;
  const int tid = threadIdx.x;
  const unsigned blk = blockIdx.x;
  const unsigned rb = (unsigned)b * NBLK2 + blk;
  const unsigned i0 = (blk * 256u + tid) * EPT;
  const size_t sbase = (size_t)b * NPTS;
  const unsigned k0 = kp.k[2 * b], k1 = kp.k[2 * b + 1];

  unsigned* p_nhi  = (unsigned*)(ws + OFF_PART);
  unsigned* p_hsum = p_nhi + PARTN;
  unsigned* p_npos = p_hsum + PARTN;
  unsigned* p_psum = p_npos + PARTN;
  unsigned* p_nwin = p_psum + PARTN;
  unsigned* wkeyg  = (unsigned*)(ws + OFF_WIN);
  unsigned* widxg  = wkeyg + (size_t)PARTN * WBCAP;
  float*    wlossg = (float*)(widxg + (size_t)PARTN * WBCAP);

  if (b == 0 && blk == 0 && tid == 0)
    *(unsigned*)(ws + 8188) = 0u;   // zero gticket (visible at kernel boundary)

  __shared__ unsigned s_n, s_nhi, s_npos, s_wn, s_fail;
  __shared__ float    s_psum, s_hsum;
  __shared__ unsigned s_si[SCAP], s_skey[SCAP];

  if (tid == 0) { s_n = 0; s_nhi = 0; s_npos = 0; s_wn = 0; s_fail = 0;
                  s_psum = 0.0f; s_hsum = 0.0f; }
  __syncthreads();

#pragma unroll
  for (int h = 0; h < 2; ++h) {
    const unsigned ib = i0 + (unsigned)h * 8u;
    const size_t off = sbase + ib;
    float4 t4a = *reinterpret_cast<const float4*>(target + off);
    float4 t4b = *reinterpret_cast<const float4*>(target + off + 4);
    float tv[8] = { t4a.x, t4a.y, t4a.z, t4a.w, t4b.x, t4b.y, t4b.z, t4b.w };

    unsigned kw[8];
#pragma unroll
    for (int r = 0; r < 8; ++r) {
      unsigned o0, o1;
      tf2x32(k0, k1, 0u, ib + (unsigned)r, o0, o1);  // partitionable: (0, i)
      kw[r] = o0 ^ o1;                                // raw word; key = kw>>9
    }

    unsigned posm = 0, him = 0, winm = 0;
#pragma unroll
    for (int r = 0; r < 8; ++r) {
      bool c  = (tv[r] == 0.0f) && (kw[r] >= THRESH_W);
      bool hi = c && (kw[r] >= HI_W);
      bool wn = c && !hi && (kw[r] >= TLO_W);
      him  |= (unsigned)hi << r;
      winm |= (unsigned)wn << r;
      posm |= (unsigned)(tv[r] == 1.0f) << r;
    }

    const unsigned flags = him | winm | posm;
    if (flags) {
      unsigned nf = (unsigned)__popc(flags);
      unsigned base = atomicAdd(&s_n, nf);
      unsigned j = 0;
#pragma unroll
      for (int r = 0; r < 8; ++r) {
        if ((flags >> r) & 1u) {
          unsigned cls = ((posm >> r) & 1u) ? 2u : (((winm >> r) & 1u) ? 1u : 0u);
          unsigned p = base + j; ++j;
          if (p < SCAP) {
            s_si[p] = (ib + (unsigned)r) | (cls << 20);
            s_skey[p] = kw[r] >> 9;
          } else {
            // inline overflow path (probability ~0): exact regardless
            float x = pred[off + r], m = mask[off + r];
            float L = lossf(x, (cls == 2u) ? 1.0f : 0.0f, m);
            if (cls == 2u) { atomicAdd(&s_psum, L); atomicAdd(&s_npos, 1u); }
            else if (cls == 0u) { atomicAdd(&s_hsum, L); atomicAdd(&s_nhi, 1u); }
            else {
              unsigned g = atomicAdd(&s_wn, 1u);
              if (g < WBCAP) {
                size_t o = (size_t)rb * WBCAP + g;
                wkeyg[o] = kw[r] >> 9; widxg[o] = ib + (unsigned)r; wlossg[o] = L;
              } else atomicOr(&s_fail, 1u);
            }
          }
        }
      }
    }
  }
  __syncthreads();

  // compacted processing: n <= SCAP < 256 -> single step
  const unsigned n = s_n < SCAP ? s_n : SCAP;
  unsigned rec = (tid < (int)n) ? s_si[tid] : 0u;
  unsigned cls = (tid < (int)n) ? (rec >> 20) : 3u;
  unsigned i = rec & 0xFFFFFu;
  float L = 0.0f;
  if (cls < 3u) {
    float x = pred[sbase + i], m = mask[sbase + i];
    L = lossf(x, (cls == 2u) ? 1.0f : 0.0f, m);
  }
  if (cls == 2u) { atomicAdd(&s_psum, L); atomicAdd(&s_npos, 1u); }
  else if (cls == 0u) { atomicAdd(&s_hsum, L); atomicAdd(&s_nhi, 1u); }
  else if (cls == 1u) {
    unsigned g = atomicAdd(&s_wn, 1u);
    if (g < WBCAP) {
      size_t o = (size_t)rb * WBCAP + g;
      wkeyg[o] = s_skey[tid]; widxg[o] = i; wlossg[o] = L;
    } else atomicOr(&s_fail, 1u);
  }
  __syncthreads();

  if (tid == 0) {   // every field written every launch -> no zeroing needed
    p_nhi[rb]  = s_nhi;
    p_hsum[rb] = __float_as_uint(s_hsum);
    p_npos[rb] = s_npos;
    p_psum[rb] = __float_as_uint(s_psum);
    unsigned wn = s_wn;
    unsigned fail = (s_fail || wn > WBCAP) ? 0x80000000u : 0u;
    p_nwin[rb] = (wn < WBCAP ? wn : WBCAP) | fail;
  }
}

// select_k: 16 blocks. Reduce partials + scan + gather window into LDS, then
// exact selection (tie: lowest idx). Full-rescan exact fallback (dead).
// Last block (gticket) computes the final 2-float output.
__global__ __launch_bounds__(256) void select_k(
    const float* __restrict__ pred, const float* __restrict__ target,
    const float* __restrict__ mask, char* __restrict__ ws,
    float* __restrict__ out, KeyPairs kp)
{
  const int b = blockIdx.x;
  const int tid = threadIdx.x;
  char* line = ws + (size_t)b * HDRB;
  unsigned* gticket = (unsigned*)(ws + 8188);

  const unsigned* p_nhi  = (const unsigned*)(ws + OFF_PART);
  const unsigned* p_hsum = p_nhi + PARTN;
  const unsigned* p_npos = p_hsum + PARTN;
  const unsigned* p_psum = p_npos + PARTN;
  const unsigned* p_nwin = p_psum + PARTN;
  const unsigned* wkeyg  = (const unsigned*)(ws + OFF_WIN);
  const unsigned* widxg  = wkeyg + (size_t)PARTN * WBCAP;
  const float*    wlossg = (const float*)(widxg + (size_t)PARTN * WBCAP);

  __shared__ unsigned skey[WCAP], sidx[WCAP];
  __shared__ float    sls[WCAP];
  __shared__ unsigned sc[256];
  __shared__ unsigned redu[256];
  __shared__ float    redf[256];
  __shared__ unsigned s_eqc, s_u1, s_tick;
  __shared__ unsigned s_eqi[BCAP];
  __shared__ float    s_eql[BCAP];
  __shared__ float    s_f;

  auto redSumU = [&](unsigned v) -> unsigned {
    redu[tid] = v; __syncthreads();
    for (int s = 128; s > 0; s >>= 1) { if (tid < s) redu[tid] += redu[tid + s]; __syncthreads(); }
    unsigned r = redu[0]; __syncthreads(); return r;
  };
  auto redSumF = [&](float v) -> float {
    redf[tid] = v; __syncthreads();
    for (int s = 128; s > 0; s >>= 1) { if (tid < s) redf[tid] += redf[tid + s]; __syncthreads(); }
    float r = redf[0]; __syncthreads(); return r;
  };

  // ---- reduce per-block partials (216 regions) ----
  unsigned mynhi = 0, mynpos = 0, mycnt = 0, myfail = 0;
  float myh = 0.0f, myp = 0.0f;
  unsigned myrb = (unsigned)b * NBLK2 + (unsigned)tid;
  if (tid < (int)NBLK2) {
    mynhi = p_nhi[myrb];
    myh   = __uint_as_float(p_hsum[myrb]);
    mynpos = p_npos[myrb];
    myp   = __uint_as_float(p_psum[myrb]);
    unsigned w = p_nwin[myrb];
    mycnt = w & 0x7FFFFFFFu;
    myfail = w >> 31;
  }
  const unsigned n_hi = redSumU(mynhi);
  const float sum_hi = redSumF(myh);
  const unsigned npos = redSumU(mynpos);
  const float pos_sum = redSumF(myp);
  const unsigned failN = redSumU(myfail);

  // exclusive scan of window counts (Hillis-Steele over 256)
  sc[tid] = mycnt; __syncthreads();
  for (int s = 1; s < 256; s <<= 1) {
    unsigned v = (tid >= s) ? sc[tid - s] : 0u;
    __syncthreads();
    sc[tid] += v;
    __syncthreads();
  }
  const unsigned nw = sc[255];
  const unsigned wbase = sc[tid] - mycnt;

  const unsigned k = (npos > 0u) ? ((100u * npos < KSEL) ? 100u * npos : KSEL) : 100u;
  const bool bad = failN || (n_hi > KSEL) || (n_hi + nw < KSEL) ||
                   (nw > WCAP) || (k < KSEL);

  float res = 0.0f;

  if (!bad) {
    // gather window entries into LDS (contiguous)
    if (tid < (int)NBLK2) {
      size_t src = (size_t)myrb * WBCAP;
      for (unsigned e = 0; e < mycnt; ++e) {
        skey[wbase + e] = wkeyg[src + e];
        sidx[wbase + e] = widxg[src + e];
        sls[wbase + e]  = wlossg[src + e];
      }
    }
    __syncthreads();
    const unsigned need = KSEL - n_hi;
    if (need == 0) res = sum_hi;
    else {
      auto cGe = [&](unsigned v) -> unsigned {
        unsigned c = 0;
        for (unsigned e = tid; e < nw; e += 256) c += (skey[e] >= v) ? 1u : 0u;
        return redSumU(c);
      };
      unsigned lo = TLO, hi = THI;                 // cGe(TLO)=nw>=need
      while (lo < hi) {
        unsigned mid = lo + (hi - lo + 1u) / 2u;
        if (cGe(mid) >= need) lo = mid; else hi = mid - 1u;
      }
      const unsigned V = lo;
      const unsigned c_gt = cGe(V + 1u);
      const unsigned m = need - c_gt;
      float s = 0.0f;
      for (unsigned e = tid; e < nw; e += 256) if (skey[e] > V) s += sls[e];
      float sum_gt = redSumF(s);
      if (tid == 0) s_eqc = 0;
      __syncthreads();
      for (unsigned e = tid; e < nw; e += 256) {
        if (skey[e] == V) {
          unsigned p = atomicAdd(&s_eqc, 1u);
          if (p < BCAP) { s_eqi[p] = sidx[e]; s_eql[p] = sls[e]; }
        }
      }
      __syncthreads();
      if (tid == 0) {
        unsigned ne = s_eqc; if (ne > BCAP) ne = BCAP;
        unsigned mm = (m < ne) ? m : ne;
        float es = 0.0f;
        for (unsigned a = 0; a < mm; ++a) {        // idx asc (LDS only)
          unsigned best = a;
          for (unsigned q = a + 1; q < ne; ++q)
            if (s_eqi[q] < s_eqi[best]) best = q;
          unsigned ti = s_eqi[a]; s_eqi[a] = s_eqi[best]; s_eqi[best] = ti;
          float tl = s_eql[a]; s_eql[a] = s_eql[best]; s_eql[best] = tl;
          es += s_eql[a];
        }
        s_f = sum_hi + sum_gt + es;
      }
      __syncthreads();
      res = s_f;
    }
  } else {
    // ---- exact fallback via full rescans (dead for this data) ----
    const float* T = target + (size_t)b * NPTS;
    const float* P = pred   + (size_t)b * NPTS;
    const float* M = mask   + (size_t)b * NPTS;
    const unsigned k0 = kp.k[2 * b], k1 = kp.k[2 * b + 1];
    auto keyOf = [&](unsigned i) -> unsigned {
      unsigned o0, o1; tf2x32(k0, k1, 0u, i, o0, o1); return (o0 ^ o1) >> 9;
    };
    auto cKeyGe = [&](unsigned v) -> unsigned {
      unsigned c = 0;
      for (unsigned i = tid; i < NPTS; i += 256)
        if (T[i] == 0.0f && keyOf(i) >= v) c++;
      return redSumU(c);
    };
    const unsigned cnt = cKeyGe(THRESH_KEY);       // exact candidate count
    const bool take_all = (cnt <= KSEL);
    const unsigned nsel = take_all ? cnt : KSEL;
    unsigned V = 0, idxcut = 0xffffffffu; float eq_sum = 0.0f;
    if (!take_all) {
      unsigned lo = THRESH_KEY, hi = KEYMAX;
      while (lo < hi) {
        unsigned mid = lo + (hi - lo + 1u) / 2u;
        if (cKeyGe(mid) >= KSEL) lo = mid; else hi = mid - 1u;
      }
      V = lo;
      unsigned c_gt = cKeyGe(V + 1u);
      unsigned needq = KSEL - c_gt;
      if (tid == 0) s_eqc = 0;
      __syncthreads();
      for (unsigned i = tid; i < NPTS; i += 256)
        if (T[i] == 0.0f && keyOf(i) == V) {
          unsigned p = atomicAdd(&s_eqc, 1u);
          if (p < BCAP) s_eqi[p] = i;
        }
      __syncthreads();
      if (tid == 0) {
        unsigned ne = s_eqc; if (ne > BCAP) ne = BCAP;
        unsigned mm = (needq < ne) ? needq : ne;
        float es = 0.0f; unsigned ic = 0xffffffffu;
        for (unsigned a = 0; a < mm; ++a) {
          unsigned best = a;
          for (unsigned q = a + 1; q < ne; ++q)
            if (s_eqi[q] < s_eqi[best]) best = q;
          unsigned ti = s_eqi[a]; s_eqi[a] = s_eqi[best]; s_eqi[best] = ti;
          es += lossf(P[s_eqi[a]], 0.0f, M[s_eqi[a]]);
        }
        if (mm > 0) ic = s_eqi[mm - 1];
        s_f = es; s_u1 = ic;
      }
      __syncthreads();
      eq_sum = s_f; idxcut = s_u1;
      __syncthreads();
    }
    if (k >= nsel) {
      float s = 0.0f;
      for (unsigned i = tid; i < NPTS; i += 256) {
        if (T[i] != 0.0f) continue;
        unsigned kk = keyOf(i);
        if (kk < THRESH_KEY) continue;
        if (take_all || kk > V) s += lossf(P[i], 0.0f, M[i]);
      }
      res = redSumF(s) + (take_all ? 0.0f : eq_sum);
    } else {
      auto cLossGe = [&](unsigned w) -> unsigned {
        unsigned c = 0;
        for (unsigned i = tid; i < NPTS; i += 256) {
          if (T[i] != 0.0f) continue;
          unsigned kk = keyOf(i);
          if (kk < THRESH_KEY) continue;
          bool sel = take_all || kk > V || (kk == V && i <= idxcut);
          if (sel && __float_as_uint(lossf(P[i], 0.0f, M[i])) >= w) c++;
        }
        return redSumU(c);
      };
      unsigned lo = 0u, hi = 0x7f7fffffu;
      while (lo < hi) {
        unsigned mid = lo + (hi - lo + 1u) / 2u;
        if (cLossGe(mid) >= k) lo = mid; else hi = mid - 1u;
      }
      unsigned cgt = cLossGe(lo + 1u);
      float s = 0.0f;
      for (unsigned i = tid; i < NPTS; i += 256) {
        if (T[i] != 0.0f) continue;
        unsigned kk = keyOf(i);
        if (kk < THRESH_KEY) continue;
        bool sel = take_all || kk > V || (kk == V && i <= idxcut);
        float L = lossf(P[i], 0.0f, M[i]);
        if (sel && __float_as_uint(L) > lo) s += L;
      }
      res = redSumF(s) + (float)(k - cgt) * __uint_as_float(lo);
    }
  }

  // publish per-sample stats + result (full overwrite), ticket, finalize
  if (tid == 0) {
    atomicExch((float*)(line + 0), pos_sum);
    atomicExch((unsigned*)(line + 4), npos);
    atomicExch((float*)(line + 256), res);
    __threadfence();
    s_tick = atomicAdd(gticket, 1u);
  }
  __syncthreads();
  if (s_tick == BATCH - 1) {
    float ps = 0.0f, ns = 0.0f;
    if (tid < BATCH) {
      char* ln = ws + (size_t)tid * HDRB;
      float pp = atomicAdd((float*)(ln + 0), 0.0f);
      unsigned np = atomicAdd((unsigned*)(ln + 4), 0u);
      float nr = atomicAdd((float*)(ln + 256), 0.0f);
      float denom = (np > 0u) ? fmaxf((float)np, 1.0f) : 1.0f;
      ps = pp / denom;
      ns = nr / denom;
    }
#pragma unroll
    for (int s = 8; s > 0; s >>= 1) {
      ps += __shfl_down(ps, s, 64);
      ns += __shfl_down(ns, s, 64);
    }
    if (tid == 0) {
      out[0] = ps / (float)BATCH;
      out[1] = ns / (float)BATCH;
    }
  }
}

extern "C" void kernel_launch(void* const* d_in, const int* in_sizes, int n_in,
                              void* d_out, int out_size, void* d_ws, size_t ws_size,
                              hipStream_t stream)
{
  const float* pred   = (const float*)d_in[0];
  const float* target = (const float*)d_in[1];
  const float* mask   = (const float*)d_in[2];
  float* out = (float*)d_out;

  const size_t FIXED = OFF_WIN + 3 * (size_t)PARTN * WBCAP * 4;   // ~1.74 MB
  if (ws_size < FIXED || out_size < 2) {
    hipMemsetAsync(d_out, 0, sizeof(float) * (out_size > 0 ? out_size : 1), stream);
    return;
  }

  char* ws = (char*)d_ws;

  KeyPairs kp;
  for (unsigned b = 0; b < BATCH; ++b) {
    unsigned o0, o1;
    tf2x32(0u, 42u, 0u, b, o0, o1);
    kp.k[2 * b] = o0; kp.k[2 * b + 1] = o1;
  }

  mono<<<dim3(NBLK2, BATCH), 256, 0, stream>>>(pred, target, mask, ws, kp);
  select_k<<<BATCH, 256, 0, stream>>>(pred, target, mask, ws, out, kp);
}

// Round 21
// 68.235 us; speedup vs baseline: 3.7744x; 1.0008x over previous
//
#include <hip/hip_runtime.h>
#include <stdint.h>

// DetectionLoss for B=16, N=884736. Output: [cls_pos_loss, cls_neg_loss].
//
// R20: 68.3us = mono 44.5 + select ~5 + ~18 dispatch/launch. mono shows
// VGPR=20 (compiler minimized pressure -> serialized halves, ~2640 instr/wave
// vs ~1400 accounted). R21: single straight-line 16-wide body (no h-loop) +
// __launch_bounds__(256,2) to un-cap VGPRs and let the scheduler pipeline
// threefry across all 16 elements. No semantic change (absmax 0.0 expected).

#define BATCH 16
#define NPTS 884736u
#define THRESH_KEY 8266976u    // candidate keys >= this (tail 0.01450)
#define THRESH_W   4232691712u // THRESH_KEY<<9 (raw-word compare)
#define KEYMAX 8388607u
#define KSEL 10000u
// cut0 = 2^23 - KSEL*121632/12822 ~= 8293746 ; margin 8000 ~= 8.5 sigma
#define TLO 8285746u
#define THI 8301746u
#define TLO_W 4242301952u      // TLO<<9
#define HI_W  4250494464u      // (THI+1)<<9 : kw>=HI_W <=> key>THI
#define WCAP 3072u             // selection window LDS cap/sample (E~1687, sd 41)
#define WBCAP 40u              // per-block window region (E~7.8, +11 sigma)
#define SCAP 192               // per-block flagged staging (E~52, +19 sigma)
#define BCAP 64
#define NBLK2 216u             // mono grid.x ; 216*4096 = NPTS
#define EPT 16u
#define HDRB 512               // per-sample header stride (hdr = 8192 B)

// ws layout: [0,8192) hdr  (line b: +0 f32 pos_sum, +4 u32 npos,
//   +256 f32 neg_result; gticket at ws+8188)
// [8192,..)   p_nhi/p_hsum/p_npos/p_psum/p_nwin : 5 x u32[3456]
// [77312,..)  wkey/widx/wloss : 3 x [3456][WBCAP]
#define OFF_PART 8192
#define PARTN (NBLK2 * BATCH)          // 3456
#define OFF_WIN (OFF_PART + 5 * PARTN * 4)

struct KeyPairs { unsigned k[2 * BATCH]; };

__host__ __device__ __forceinline__ void tf2x32(unsigned k0, unsigned k1,
                                                unsigned x0, unsigned x1,
                                                unsigned& o0, unsigned& o1)
{
  unsigned ks0 = k0, ks1 = k1, ks2 = k0 ^ k1 ^ 0x1BD11BDAu;
  x0 += ks0; x1 += ks1;
#define TF_R(r) { x0 += x1; x1 = __builtin_rotateleft32(x1, r); x1 ^= x0; }
  TF_R(13) TF_R(15) TF_R(26) TF_R(6)
  x0 += ks1; x1 += ks2 + 1u;
  TF_R(17) TF_R(29) TF_R(16) TF_R(24)
  x0 += ks2; x1 += ks0 + 2u;
  TF_R(13) TF_R(15) TF_R(26) TF_R(6)
  x0 += ks0; x1 += ks1 + 3u;
  TF_R(17) TF_R(29) TF_R(16) TF_R(24)
  x0 += ks1; x1 += ks2 + 4u;
  TF_R(13) TF_R(15) TF_R(26) TF_R(6)
  x0 += ks2; x1 += ks0 + 5u;
#undef TF_R
  o0 = x0; o1 = x1;
}

__device__ __forceinline__ float lossf(float x, float t, float m)
{
  float e  = __expf(-x);
  float p  = __fdividef(1.0f, 1.0f + e);
  p = fminf(fmaxf(p, 1e-4f), 1.0f - 1e-4f);
  bool is_pos = (t == 1.0f);
  float alpha = is_pos ? 0.75f : 0.25f;
  float pw = is_pos ? (1.0f - p) : p;
  float soft = __logf(1.0f + __expf(-fabsf(x)));
  float bce = fmaxf(x, 0.0f) - x * t + soft;
  float L = (m == 0.0f) ? alpha * pw * pw * bce : 0.0f;
  if (is_pos && p < 0.8f) L *= 4.0f;
  if (!is_pos && p > 0.5f)
    L *= 1.5f + fminf(fmaxf((p - 0.5f) * 5.0f, 0.0f), 1.0f) * 0.5f;
  return L;
}

__global__ __launch_bounds__(256, 2) void mono(
    const float* __restrict__ pred, const float* __restrict__ target,
    const float* __restrict__ mask, char* __restrict__ ws, KeyPairs kp)
{
  const int b = blockIdx.y;
  const int tid = threadIdx.x;
  const unsigned blk = blockIdx.x;
  const unsigned rb = (unsigned)b * NBLK2 + blk;
  const unsigned i0 = (blk * 256u + tid) * EPT;
  const size_t sbase = (size_t)b * NPTS;
  const size_t off = sbase + i0;
  const unsigned k0 = kp.k[2 * b], k1 = kp.k[2 * b + 1];

  unsigned* p_nhi  = (unsigned*)(ws + OFF_PART);
  unsigned* p_hsum = p_nhi + PARTN;
  unsigned* p_npos = p_hsum + PARTN;
  unsigned* p_psum = p_npos + PARTN;
  unsigned* p_nwin = p_psum + PARTN;
  unsigned* wkeyg  = (unsigned*)(ws + OFF_WIN);
  unsigned* widxg  = wkeyg + (size_t)PARTN * WBCAP;
  float*    wlossg = (float*)(widxg + (size_t)PARTN * WBCAP);

  if (b == 0 && blk == 0 && tid == 0)
    *(unsigned*)(ws + 8188) = 0u;   // zero gticket (visible at kernel boundary)

  __shared__ unsigned s_n, s_nhi, s_npos, s_wn, s_fail;
  __shared__ float    s_psum, s_hsum;
  __shared__ unsigned s_si[SCAP], s_skey[SCAP];

  if (tid == 0) { s_n = 0; s_nhi = 0; s_npos = 0; s_wn = 0; s_fail = 0;
                  s_psum = 0.0f; s_hsum = 0.0f; }
  __syncthreads();

  // ---- straight-line 16-wide body ----
  float4 t4a = *reinterpret_cast<const float4*>(target + off);
  float4 t4b = *reinterpret_cast<const float4*>(target + off + 4);
  float4 t4c = *reinterpret_cast<const float4*>(target + off + 8);
  float4 t4d = *reinterpret_cast<const float4*>(target + off + 12);
  float tv[16] = { t4a.x, t4a.y, t4a.z, t4a.w, t4b.x, t4b.y, t4b.z, t4b.w,
                   t4c.x, t4c.y, t4c.z, t4c.w, t4d.x, t4d.y, t4d.z, t4d.w };

  unsigned kw[16];
#pragma unroll
  for (int r = 0; r < 16; ++r) {
    unsigned o0, o1;
    tf2x32(k0, k1, 0u, i0 + (unsigned)r, o0, o1);   // partitionable: (0, i)
    kw[r] = o0 ^ o1;                                 // raw word; key = kw>>9
  }

  unsigned posm = 0, him = 0, winm = 0;
#pragma unroll
  for (int r = 0; r < 16; ++r) {
    bool c  = (tv[r] == 0.0f) && (kw[r] >= THRESH_W);
    bool hi = c && (kw[r] >= HI_W);
    bool wn = c && !hi && (kw[r] >= TLO_W);
    him  |= (unsigned)hi << r;
    winm |= (unsigned)wn << r;
    posm |= (unsigned)(tv[r] == 1.0f) << r;
  }

  const unsigned flags = him | winm | posm;
  if (flags) {
    unsigned nf = (unsigned)__popc(flags);
    unsigned base = atomicAdd(&s_n, nf);
    unsigned j = 0;
#pragma unroll
    for (int r = 0; r < 16; ++r) {
      if ((flags >> r) & 1u) {
        unsigned cls = ((posm >> r) & 1u) ? 2u : (((winm >> r) & 1u) ? 1u : 0u);
        unsigned p = base + j; ++j;
        if (p < SCAP) {
          s_si[p] = (i0 + (unsigned)r) | (cls << 20);
          s_skey[p] = kw[r] >> 9;
        } else {
          // inline overflow path (probability ~0): exact regardless
          float x = pred[off + r], m = mask[off + r];
          float L = lossf(x, (cls == 2u) ? 1.0f : 0.0f, m);
          if (cls == 2u) { atomicAdd(&s_psum, L); atomicAdd(&s_npos, 1u); }
          else if (cls == 0u) { atomicAdd(&s_hsum, L); atomicAdd(&s_nhi, 1u); }
          else {
            unsigned g = atomicAdd(&s_wn, 1u);
            if (g < WBCAP) {
              size_t o = (size_t)rb * WBCAP + g;
              wkeyg[o] = kw[r] >> 9; widxg[o] = i0 + (unsigned)r; wlossg[o] = L;
            } else atomicOr(&s_fail, 1u);
          }
        }
      }
    }
  }
  __syncthreads();

  // compacted processing: n <= SCAP < 256 -> single step
  const unsigned n = s_n < SCAP ? s_n : SCAP;
  unsigned rec = (tid < (int)n) ? s_si[tid] : 0u;
  unsigned cls = (tid < (int)n) ? (rec >> 20) : 3u;
  unsigned i = rec & 0xFFFFFu;
  float L = 0.0f;
  if (cls < 3u) {
    float x = pred[sbase + i], m = mask[sbase + i];
    L = lossf(x, (cls == 2u) ? 1.0f : 0.0f, m);
  }
  if (cls == 2u) { atomicAdd(&s_psum, L); atomicAdd(&s_npos, 1u); }
  else if (cls == 0u) { atomicAdd(&s_hsum, L); atomicAdd(&s_nhi, 1u); }
  else if (cls == 1u) {
    unsigned g = atomicAdd(&s_wn, 1u);
    if (g < WBCAP) {
      size_t o = (size_t)rb * WBCAP + g;
      wkeyg[o] = s_skey[tid]; widxg[o] = i; wlossg[o] = L;
    } else atomicOr(&s_fail, 1u);
  }
  __syncthreads();

  if (tid == 0) {   // every field written every launch -> no zeroing needed
    p_nhi[rb]  = s_nhi;
    p_hsum[rb] = __float_as_uint(s_hsum);
    p_npos[rb] = s_npos;
    p_psum[rb] = __float_as_uint(s_psum);
    unsigned wn = s_wn;
    unsigned fail = (s_fail || wn > WBCAP) ? 0x80000000u : 0u;
    p_nwin[rb] = (wn < WBCAP ? wn : WBCAP) | fail;
  }
}

// select_k: 16 blocks. Reduce partials + scan + gather window into LDS, then
// exact selection (tie: lowest idx). Full-rescan exact fallback (dead).
// Last block (gticket) computes the final 2-float output.
__global__ __launch_bounds__(256) void select_k(
    const float* __restrict__ pred, const float* __restrict__ target,
    const float* __restrict__ mask, char* __restrict__ ws,
    float* __restrict__ out, KeyPairs kp)
{
  const int b = blockIdx.x;
  const int tid = threadIdx.x;
  char* line = ws + (size_t)b * HDRB;
  unsigned* gticket = (unsigned*)(ws + 8188);

  const unsigned* p_nhi  = (const unsigned*)(ws + OFF_PART);
  const unsigned* p_hsum = p_nhi + PARTN;
  const unsigned* p_npos = p_hsum + PARTN;
  const unsigned* p_psum = p_npos + PARTN;
  const unsigned* p_nwin = p_psum + PARTN;
  const unsigned* wkeyg  = (const unsigned*)(ws + OFF_WIN);
  const unsigned* widxg  = wkeyg + (size_t)PARTN * WBCAP;
  const float*    wlossg = (const float*)(widxg + (size_t)PARTN * WBCAP);

  __shared__ unsigned skey[WCAP], sidx[WCAP];
  __shared__ float    sls[WCAP];
  __shared__ unsigned sc[256];
  __shared__ unsigned redu[256];
  __shared__ float    redf[256];
  __shared__ unsigned s_eqc, s_u1, s_tick;
  __shared__ unsigned s_eqi[BCAP];
  __shared__ float    s_eql[BCAP];
  __shared__ float    s_f;

  auto redSumU = [&](unsigned v) -> unsigned {
    redu[tid] = v; __syncthreads();
    for (int s = 128; s > 0; s >>= 1) { if (tid < s) redu[tid] += redu[tid + s]; __syncthreads(); }
    unsigned r = redu[0]; __syncthreads(); return r;
  };
  auto redSumF = [&](float v) -> float {
    redf[tid] = v; __syncthreads();
    for (int s = 128; s > 0; s >>= 1) { if (tid < s) redf[tid] += redf[tid + s]; __syncthreads(); }
    float r = redf[0]; __syncthreads(); return r;
  };

  // ---- reduce per-block partials (216 regions) ----
  unsigned mynhi = 0, mynpos = 0, mycnt = 0, myfail = 0;
  float myh = 0.0f, myp = 0.0f;
  unsigned myrb = (unsigned)b * NBLK2 + (unsigned)tid;
  if (tid < (int)NBLK2) {
    mynhi = p_nhi[myrb];
    myh   = __uint_as_float(p_hsum[myrb]);
    mynpos = p_npos[myrb];
    myp   = __uint_as_float(p_psum[myrb]);
    unsigned w = p_nwin[myrb];
    mycnt = w & 0x7FFFFFFFu;
    myfail = w >> 31;
  }
  const unsigned n_hi = redSumU(mynhi);
  const float sum_hi = redSumF(myh);
  const unsigned npos = redSumU(mynpos);
  const float pos_sum = redSumF(myp);
  const unsigned failN = redSumU(myfail);

  // exclusive scan of window counts (Hillis-Steele over 256)
  sc[tid] = mycnt; __syncthreads();
  for (int s = 1; s < 256; s <<= 1) {
    unsigned v = (tid >= s) ? sc[tid - s] : 0u;
    __syncthreads();
    sc[tid] += v;
    __syncthreads();
  }
  const unsigned nw = sc[255];
  const unsigned wbase = sc[tid] - mycnt;

  const unsigned k = (npos > 0u) ? ((100u * npos < KSEL) ? 100u * npos : KSEL) : 100u;
  const bool bad = failN || (n_hi > KSEL) || (n_hi + nw < KSEL) ||
                   (nw > WCAP) || (k < KSEL);

  float res = 0.0f;

  if (!bad) {
    // gather window entries into LDS (contiguous)
    if (tid < (int)NBLK2) {
      size_t src = (size_t)myrb * WBCAP;
      for (unsigned e = 0; e < mycnt; ++e) {
        skey[wbase + e] = wkeyg[src + e];
        sidx[wbase + e] = widxg[src + e];
        sls[wbase + e]  = wlossg[src + e];
      }
    }
    __syncthreads();
    const unsigned need = KSEL - n_hi;
    if (need == 0) res = sum_hi;
    else {
      auto cGe = [&](unsigned v) -> unsigned {
        unsigned c = 0;
        for (unsigned e = tid; e < nw; e += 256) c += (skey[e] >= v) ? 1u : 0u;
        return redSumU(c);
      };
      unsigned lo = TLO, hi = THI;                 // cGe(TLO)=nw>=need
      while (lo < hi) {
        unsigned mid = lo + (hi - lo + 1u) / 2u;
        if (cGe(mid) >= need) lo = mid; else hi = mid - 1u;
      }
      const unsigned V = lo;
      const unsigned c_gt = cGe(V + 1u);
      const unsigned m = need - c_gt;
      float s = 0.0f;
      for (unsigned e = tid; e < nw; e += 256) if (skey[e] > V) s += sls[e];
      float sum_gt = redSumF(s);
      if (tid == 0) s_eqc = 0;
      __syncthreads();
      for (unsigned e = tid; e < nw; e += 256) {
        if (skey[e] == V) {
          unsigned p = atomicAdd(&s_eqc, 1u);
          if (p < BCAP) { s_eqi[p] = sidx[e]; s_eql[p] = sls[e]; }
        }
      }
      __syncthreads();
      if (tid == 0) {
        unsigned ne = s_eqc; if (ne > BCAP) ne = BCAP;
        unsigned mm = (m < ne) ? m : ne;
        float es = 0.0f;
        for (unsigned a = 0; a < mm; ++a) {        // idx asc (LDS only)
          unsigned best = a;
          for (unsigned q = a + 1; q < ne; ++q)
            if (s_eqi[q] < s_eqi[best]) best = q;
          unsigned ti = s_eqi[a]; s_eqi[a] = s_eqi[best]; s_eqi[best] = ti;
          float tl = s_eql[a]; s_eql[a] = s_eql[best]; s_eql[best] = tl;
          es += s_eql[a];
        }
        s_f = sum_hi + sum_gt + es;
      }
      __syncthreads();
      res = s_f;
    }
  } else {
    // ---- exact fallback via full rescans (dead for this data) ----
    const float* T = target + (size_t)b * NPTS;
    const float* P = pred   + (size_t)b * NPTS;
    const float* M = mask   + (size_t)b * NPTS;
    const unsigned k0 = kp.k[2 * b], k1 = kp.k[2 * b + 1];
    auto keyOf = [&](unsigned i) -> unsigned {
      unsigned o0, o1; tf2x32(k0, k1, 0u, i, o0, o1); return (o0 ^ o1) >> 9;
    };
    auto cKeyGe = [&](unsigned v) -> unsigned {
      unsigned c = 0;
      for (unsigned i = tid; i < NPTS; i += 256)
        if (T[i] == 0.0f && keyOf(i) >= v) c++;
      return redSumU(c);
    };
    const unsigned cnt = cKeyGe(THRESH_KEY);       // exact candidate count
    const bool take_all = (cnt <= KSEL);
    const unsigned nsel = take_all ? cnt : KSEL;
    unsigned V = 0, idxcut = 0xffffffffu; float eq_sum = 0.0f;
    if (!take_all) {
      unsigned lo = THRESH_KEY, hi = KEYMAX;
      while (lo < hi) {
        unsigned mid = lo + (hi - lo + 1u) / 2u;
        if (cKeyGe(mid) >= KSEL) lo = mid; else hi = mid - 1u;
      }
      V = lo;
      unsigned c_gt = cKeyGe(V + 1u);
      unsigned needq = KSEL - c_gt;
      if (tid == 0) s_eqc = 0;
      __syncthreads();
      for (unsigned i = tid; i < NPTS; i += 256)
        if (T[i] == 0.0f && keyOf(i) == V) {
          unsigned p = atomicAdd(&s_eqc, 1u);
          if (p < BCAP) s_eqi[p] = i;
        }
      __syncthreads();
      if (tid == 0) {
        unsigned ne = s_eqc; if (ne > BCAP) ne = BCAP;
        unsigned mm = (needq < ne) ? needq : ne;
        float es = 0.0f; unsigned ic = 0xffffffffu;
        for (unsigned a = 0; a < mm; ++a) {
          unsigned best = a;
          for (unsigned q = a + 1; q < ne; ++q)
            if (s_eqi[q] < s_eqi[best]) best = q;
          unsigned ti = s_eqi[a]; s_eqi[a] = s_eqi[best]; s_eqi[best] = ti;
          es += lossf(P[s_eqi[a]], 0.0f, M[s_eqi[a]]);
        }
        if (mm > 0) ic = s_eqi[mm - 1];
        s_f = es; s_u1 = ic;
      }
      __syncthreads();
      eq_sum = s_f; idxcut = s_u1;
      __syncthreads();
    }
    if (k >= nsel) {
      float s = 0.0f;
      for (unsigned i = tid; i < NPTS; i += 256) {
        if (T[i] != 0.0f) continue;
        unsigned kk = keyOf(i);
        if (kk < THRESH_KEY) continue;
        if (take_all || kk > V) s += lossf(P[i], 0.0f, M[i]);
      }
      res = redSumF(s) + (take_all ? 0.0f : eq_sum);
    } else {
      auto cLossGe = [&](unsigned w) -> unsigned {
        unsigned c = 0;
        for (unsigned i = tid; i < NPTS; i += 256) {
          if (T[i] != 0.0f) continue;
          unsigned kk = keyOf(i);
          if (kk < THRESH_KEY) continue;
          bool sel = take_all || kk > V || (kk == V && i <= idxcut);
          if (sel && __float_as_uint(lossf(P[i], 0.0f, M[i])) >= w) c++;
        }
        return redSumU(c);
      };
      unsigned lo = 0u, hi = 0x7f7fffffu;
      while (lo < hi) {
        unsigned mid = lo + (hi - lo + 1u) / 2u;
        if (cLossGe(mid) >= k) lo = mid; else hi = mid - 1u;
      }
      unsigned cgt = cLossGe(lo + 1u);
      float s = 0.0f;
      for (unsigned i = tid; i < NPTS; i += 256) {
        if (T[i] != 0.0f) continue;
        unsigned kk = keyOf(i);
        if (kk < THRESH_KEY) continue;
        bool sel = take_all || kk > V || (kk == V && i <= idxcut);
        float L = lossf(P[i], 0.0f, M[i]);
        if (sel && __float_as_uint(L) > lo) s += L;
      }
      res = redSumF(s) + (float)(k - cgt) * __uint_as_float(lo);
    }
  }

  // publish per-sample stats + result (full overwrite), ticket, finalize
  if (tid == 0) {
    atomicExch((float*)(line + 0), pos_sum);
    atomicExch((unsigned*)(line + 4), npos);
    atomicExch((float*)(line + 256), res);
    __threadfence();
    s_tick = atomicAdd(gticket, 1u);
  }
  __syncthreads();
  if (s_tick == BATCH - 1) {
    float ps = 0.0f, ns = 0.0f;
    if (tid < BATCH) {
      char* ln = ws + (size_t)tid * HDRB;
      float pp = atomicAdd((float*)(ln + 0), 0.0f);
      unsigned np = atomicAdd((unsigned*)(ln + 4), 0u);
      float nr = atomicAdd((float*)(ln + 256), 0.0f);
      float denom = (np > 0u) ? fmaxf((float)np, 1.0f) : 1.0f;
      ps = pp / denom;
      ns = nr / denom;
    }
#pragma unroll
    for (int s = 8; s > 0; s >>= 1) {
      ps += __shfl_down(ps, s, 64);
      ns += __shfl_down(ns, s, 64);
    }
    if (tid == 0) {
      out[0] = ps / (float)BATCH;
      out[1] = ns / (float)BATCH;
    }
  }
}

extern "C" void kernel_launch(void* const* d_in, const int* in_sizes, int n_in,
                              void* d_out, int out_size, void* d_ws, size_t ws_size,
                              hipStream_t stream)
{
  const float* pred   = (const float*)d_in[0];
  const float* target = (const float*)d_in[1];
  const float* mask   = (const float*)d_in[2];
  float* out = (float*)d_out;

  const size_t FIXED = OFF_WIN + 3 * (size_t)PARTN * WBCAP * 4;   // ~1.74 MB
  if (ws_size < FIXED || out_size < 2) {
    hipMemsetAsync(d_out, 0, sizeof(float) * (out_size > 0 ? out_size : 1), stream);
    return;
  }

  char* ws = (char*)d_ws;

  KeyPairs kp;
  for (unsigned b = 0; b < BATCH; ++b) {
    unsigned o0, o1;
    tf2x32(0u, 42u, 0u, b, o0, o1);
    kp.k[2 * b] = o0; kp.k[2 * b + 1] = o1;
  }

  mono<<<dim3(NBLK2, BATCH), 256, 0, stream>>>(pred, target, mask, ws, kp);
  select_k<<<BATCH, 256, 0, stream>>>(pred, target, mask, ws, out, kp);
}